// Round 6
// baseline (415.430 us; speedup 1.0000x reference)
//
#include <hip/hip_runtime.h>
#include <hip/hip_bf16.h>
#include <math.h>

// Problem constants
#define HH 80
#define WW 80
#define NPIX 6400          // H*W
#define CC 36              // 6 labels x 6 channels
#define CCP 48             // padded: label l at channels l*8.. ; c==6 is ones->norm
#define NC 6
#define NUM_ITER 5
#define JS 20              // j-slices
#define SLICE (NPIX / JS)  // 320
#define JTILES (SLICE / 32)// 10
#define IBLK 100           // i-blocks (4 waves x 16 i = 64 i each)

typedef __attribute__((ext_vector_type(8))) short bfrag;   // 8 bf16 (4 VGPR)
typedef __attribute__((ext_vector_type(4))) float f32x4;   // MFMA acc
typedef __attribute__((ext_vector_type(2))) float f32x2;   // packed f32 math

// coords prescaled so bilateral w = exp2(-(dy^2+dx^2+d0^2+d1^2+d2^2))
// spatial  w = exp2(-RS*(dy^2+dx^2)), RS = 128/18
__device__ __constant__ const float kSA = 0.08838834764831845f;  // sqrt(1/(128*ln2))
__device__ __constant__ const float kSB = 5.663898078577187f;    // sqrt(1/(0.045*ln2))
__device__ __constant__ const float kRS = 7.11111111f;           // 128/18

__device__ inline unsigned short f2bf(float f) {
    unsigned u = __builtin_bit_cast(unsigned, f);
    unsigned r = (u + 0x7FFFu + ((u >> 16) & 1u)) >> 16;
    return (unsigned short)r;
}

// ---------------------------------------------------------------------------
// init: pf SoA prescaled (y,x,f0,f1,f2); sm0 = softmax(unary) in fp32 [N][36]
// and bf16-transposed smbT [48][N] with rows l*8+6 = 1.0, l*8+7 = 0.
// Also zeroes out[6] (d_out is poisoned before every call).
// ---------------------------------------------------------------------------
__global__ __launch_bounds__(256) void k_init(const float* __restrict__ unary,
                                              const float* __restrict__ feat,
                                              float* __restrict__ sm,
                                              unsigned short* __restrict__ smbT,
                                              float* __restrict__ pf,
                                              float* __restrict__ out) {
    int i = blockIdx.x * 256 + threadIdx.x;
    if (blockIdx.x == 0 && threadIdx.x < NC) out[threadIdx.x] = 0.f;
    if (i >= NPIX) return;
    int y = i / WW, x = i - y * WW;
    pf[0 * NPIX + i] = kSA * (float)y;
    pf[1 * NPIX + i] = kSA * (float)x;
    pf[2 * NPIX + i] = kSB * feat[i * 3 + 0];
    pf[3 * NPIX + i] = kSB * feat[i * 3 + 1];
    pf[4 * NPIX + i] = kSB * feat[i * 3 + 2];
    float v[NC], mx = -1e30f;
#pragma unroll
    for (int c = 0; c < NC; c++) { v[c] = unary[i * NC + c]; mx = fmaxf(mx, v[c]); }
    float sum = 0.f;
#pragma unroll
    for (int c = 0; c < NC; c++) { v[c] = __expf(v[c] - mx); sum += v[c]; }
    float inv = 1.f / sum;
#pragma unroll
    for (int l = 0; l < NC; l++) {
#pragma unroll
        for (int c = 0; c < NC; c++) {
            float s = v[c] * inv;
            sm[(size_t)i * CC + l * NC + c] = s;
            smbT[(size_t)(l * 8 + c) * NPIX + i] = f2bf(s);
        }
        smbT[(size_t)(l * 8 + 6) * NPIX + i] = 0x3F80;  // ones -> normalizer
        smbT[(size_t)(l * 8 + 7) * NPIX + i] = 0;
    }
}

// ---------------------------------------------------------------------------
// N^2 MFMA pass, both kernels, packed-f32 weight math.
// Block: 4 waves; wave owns ONE i-tile (16 i); loops j over its slice.
// Grid = IBLK x JS = 2000 blocks -> ~8 waves/SIMD.
// A layout: row = lane&15, k = 8*(lane>>4)+e ; B: col = lane&15, same k;
// D: col = lane&15, row = 4*(lane>>4)+reg   (verified rounds 4-5)
// ---------------------------------------------------------------------------
__global__ __launch_bounds__(256) void k_bil(const unsigned short* __restrict__ smbT,
                                             const float* __restrict__ pf,
                                             float* __restrict__ part_b,
                                             float* __restrict__ part_s) {
    int tid = threadIdx.x, bid = blockIdx.x;
    int s = bid / IBLK, ib = bid - s * IBLK;
    int j00 = s * SLICE;
    int wv = tid >> 6, lane = tid & 63, r = lane & 15, gq = lane >> 4;
    int it0 = (ib * 4 + wv) * 16;
    int iA = it0 + r;

    const float* py = pf;
    const float* px = pf + NPIX;
    const float* p0 = pf + 2 * NPIX;
    const float* p1 = pf + 3 * NPIX;
    const float* p2 = pf + 4 * NPIX;

    f32x2 yA = {py[iA], py[iA]};
    f32x2 xA = {px[iA], px[iA]};
    f32x2 fA0 = {p0[iA], p0[iA]};
    f32x2 fA1 = {p1[iA], p1[iA]};
    f32x2 fA2 = {p2[iA], p2[iA]};
    const f32x2 rs2 = {kRS, kRS};

    f32x4 ab[3], as_[3];
#pragma unroll
    for (int t = 0; t < 3; t++) {
        ab[t] = (f32x4){0.f, 0.f, 0.f, 0.f};
        as_[t] = (f32x4){0.f, 0.f, 0.f, 0.f};
    }

    for (int jt = 0; jt < JTILES; jt++) {
        int jb = j00 + jt * 32 + 8 * gq;   // this lane's k-base (8-aligned)
        const f32x2* yj = (const f32x2*)(py + jb);
        const f32x2* xj = (const f32x2*)(px + jb);
        const f32x2* u0 = (const f32x2*)(p0 + jb);
        const f32x2* u1 = (const f32x2*)(p1 + jb);
        const f32x2* u2 = (const f32x2*)(p2 + jb);
        bfrag Bf[3];
#pragma unroll
        for (int t = 0; t < 3; t++)
            Bf[t] = *(const bfrag*)(smbT + (size_t)(16 * t + r) * NPIX + jb);

        float wb[8], wsp[8];
#pragma unroll
        for (int p = 0; p < 4; p++) {          // pairs of j -> v_pk_* math
            f32x2 dy = yA - yj[p];
            f32x2 dx = xA - xj[p];
            f32x2 sp = dy * dy;
            sp = dx * dx + sp;
            f32x2 d0 = fA0 - u0[p];
            f32x2 d1 = fA1 - u1[p];
            f32x2 d2 = fA2 - u2[p];
            f32x2 a = d0 * d0 + sp;
            a = d1 * d1 + a;
            a = d2 * d2 + a;
            f32x2 aspat = rs2 * sp;
            wb[2 * p]     = __builtin_amdgcn_exp2f(-a[0]);
            wb[2 * p + 1] = __builtin_amdgcn_exp2f(-a[1]);
            wsp[2 * p]     = __builtin_amdgcn_exp2f(-aspat[0]);
            wsp[2 * p + 1] = __builtin_amdgcn_exp2f(-aspat[1]);
        }
        union { unsigned u[4]; bfrag v; } Ab, As;
#pragma unroll
        for (int m = 0; m < 4; m++) {
            asm("v_cvt_pk_bf16_f32 %0, %1, %2" : "=v"(Ab.u[m]) : "v"(wb[2 * m]), "v"(wb[2 * m + 1]));
            asm("v_cvt_pk_bf16_f32 %0, %1, %2" : "=v"(As.u[m]) : "v"(wsp[2 * m]), "v"(wsp[2 * m + 1]));
        }
#pragma unroll
        for (int t = 0; t < 3; t++) {
            ab[t]  = __builtin_amdgcn_mfma_f32_16x16x32_bf16(Ab.v, Bf[t], ab[t], 0, 0, 0);
            as_[t] = __builtin_amdgcn_mfma_f32_16x16x32_bf16(As.v, Bf[t], as_[t], 0, 0, 0);
        }
    }
#pragma unroll
    for (int t = 0; t < 3; t++)
#pragma unroll
        for (int d = 0; d < 4; d++) {
            int irow = it0 + 4 * gq + d;
            size_t o = ((size_t)s * NPIX + irow) * CCP + 16 * t + r;
            part_b[o] = ab[t][d];
            part_s[o] = as_[t][d];
        }
}

// ---------------------------------------------------------------------------
// update: reduce parts (norm = channel l*8+6), message, pairwise, q, softmax.
// LAST: compute ELBO partial sums directly into out[6] (no sm/q write).
// Grid is exactly 150*256 == NPIX*NC (no early returns; safe __syncthreads).
// ---------------------------------------------------------------------------
template <bool LAST>
__global__ __launch_bounds__(256) void k_update(const float* __restrict__ part_b,
                                                const float* __restrict__ part_s,
                                                const float* __restrict__ unary,
                                                const float* __restrict__ SW,
                                                const float* __restrict__ BW,
                                                const float* __restrict__ CM,
                                                const float* __restrict__ LG,
                                                float* __restrict__ sm,
                                                unsigned short* __restrict__ smbT,
                                                float* __restrict__ out) {
    __shared__ float sSW[36], sBW[36], sCM[36], sLG[36];
    __shared__ float bins[NC];
    int tid = threadIdx.x;
    if (tid < 36) { sSW[tid] = SW[tid]; sBW[tid] = BW[tid]; sCM[tid] = CM[tid]; sLG[tid] = LG[tid]; }
    if (LAST && tid < NC) bins[tid] = 0.f;
    __syncthreads();
    int t = blockIdx.x * 256 + tid;  // t = n*6 + l
    int n = t / NC, l = t - n * NC;

    float fb[NC], fs[NC], nb = 0.f, ns = 0.f;
#pragma unroll
    for (int c = 0; c < NC; c++) { fb[c] = 0.f; fs[c] = 0.f; }
    for (int s = 0; s < JS; s++) {
        const float4* pb = (const float4*)(part_b + ((size_t)s * NPIX + n) * CCP + l * 8);
        const float4* ps = (const float4*)(part_s + ((size_t)s * NPIX + n) * CCP + l * 8);
        float4 b0 = pb[0], b1 = pb[1];
        float4 s0 = ps[0], s1 = ps[1];
        fb[0] += b0.x; fb[1] += b0.y; fb[2] += b0.z; fb[3] += b0.w;
        fb[4] += b1.x; fb[5] += b1.y; nb += b1.z;
        fs[0] += s0.x; fs[1] += s0.y; fs[2] += s0.z; fs[3] += s0.w;
        fs[4] += s1.x; fs[5] += s1.y; ns += s1.z;
    }
    float invb = 1.f / nb, invs = 1.f / ns;
#pragma unroll
    for (int c = 0; c < NC; c++) { fb[c] *= invb; fs[c] *= invs; }

    float m[NC];
#pragma unroll
    for (int c = 0; c < NC; c++) {
        float a = 0.f;
#pragma unroll
        for (int cp = 0; cp < NC; cp++)
            a += sSW[c * NC + cp] * fs[cp] + sBW[c * NC + cp] * fb[cp];
        m[c] = a;
    }
    const float* up = unary + (size_t)n * NC;
    if (!LAST) {
        float qv[NC], mxq = -1e30f;
#pragma unroll
        for (int c = 0; c < NC; c++) {
            float pw = 0.f;
#pragma unroll
            for (int cp = 0; cp < NC; cp++) pw += sCM[c * NC + cp] * m[cp];
            qv[c] = up[c] + sLG[c * NC + l] - pw;
            mxq = fmaxf(mxq, qv[c]);
        }
        float e[NC], ssum = 0.f;
#pragma unroll
        for (int c = 0; c < NC; c++) { e[c] = __expf(qv[c] - mxq); ssum += e[c]; }
        float inv = 1.f / ssum;
        float* sp = sm + (size_t)n * CC + l * NC;
#pragma unroll
        for (int c = 0; c < NC; c++) {
            float sv = e[c] * inv;
            sp[c] = sv;
            smbT[(size_t)(l * 8 + c) * NPIX + n] = f2bf(sv);
        }
    } else {
        const float* sp = sm + (size_t)n * CC + l * NC;
        float v = 0.f;
#pragma unroll
        for (int c = 0; c < NC; c++) {
            float sv = sp[c];
            v += sv * (up[c] + sLG[c * NC + l] - logf(sv + 1e-10f) - m[c]);
        }
        atomicAdd(&bins[l], v);
        __syncthreads();
        if (tid < NC) atomicAdd(&out[tid], bins[tid]);
    }
}

// ---------------------------------------------------------------------------
extern "C" void kernel_launch(void* const* d_in, const int* in_sizes, int n_in,
                              void* d_out, int out_size, void* d_ws, size_t ws_size,
                              hipStream_t stream) {
    const float* unary = (const float*)d_in[0];  // [N][6]
    const float* feat  = (const float*)d_in[1];  // [N][3]
    const float* CM    = (const float*)d_in[2];  // [6][6]
    const float* LG    = (const float*)d_in[3];
    const float* SW    = (const float*)d_in[4];
    const float* BW    = (const float*)d_in[5];
    float* out = (float*)d_out;

    float* ws = (float*)d_ws;
    float* pf = ws;                                     // 5N
    float* sm = pf + (size_t)5 * NPIX;                  // 36N fp32
    unsigned short* smbT = (unsigned short*)(sm + (size_t)CC * NPIX);  // 48 x N bf16
    float* part_b = ws + (size_t)65 * NPIX;             // JS*N*48
    float* part_s = part_b + (size_t)JS * NPIX * CCP;   // JS*N*48

    k_init<<<25, 256, 0, stream>>>(unary, feat, sm, smbT, pf, out);

    for (int it = 0; it < NUM_ITER; it++) {
        k_bil<<<IBLK * JS, 256, 0, stream>>>(smbT, pf, part_b, part_s);
        if (it < NUM_ITER - 1)
            k_update<false><<<150, 256, 0, stream>>>(part_b, part_s, unary,
                                                     SW, BW, CM, LG, sm, smbT, out);
        else
            k_update<true><<<150, 256, 0, stream>>>(part_b, part_s, unary,
                                                    SW, BW, CM, LG, sm, smbT, out);
    }
}

// Round 7
// 278.381 us; speedup vs baseline: 1.4923x; 1.4923x over previous
//
#include <hip/hip_runtime.h>
#include <hip/hip_bf16.h>
#include <math.h>

// Problem constants
#define HH 80
#define WW 80
#define NPIX 6400          // H*W
#define CC 36              // 6 labels x 6 channels
#define CCP 48             // padded: label l at dwords l*8.. ; c==6 is ones->norm
#define NC 6
#define NUM_ITER 5
#define JS 20              // j-slices
#define SLICE (NPIX / JS)  // 320
#define JTILES (SLICE / 32)// 10
#define IBLK 50            // i-blocks: 4 waves x 2 i-tiles x 16 = 128 i per block

typedef __attribute__((ext_vector_type(8))) short bfrag;   // 8 bf16 (4 VGPR)
typedef __attribute__((ext_vector_type(4))) float f32x4;
typedef __attribute__((ext_vector_type(2))) float f32x2;

// coords prescaled so bilateral w = exp2(-(dy^2+dx^2+d0^2+d1^2+d2^2))
// spatial  w = exp2(-RS*(dy^2+dx^2)), RS = 128/18
__device__ __constant__ const float kSA = 0.08838834764831845f;  // sqrt(1/(128*ln2))
__device__ __constant__ const float kSB = 5.663898078577187f;    // sqrt(1/(0.045*ln2))
__device__ __constant__ const float kRS = 7.11111111f;           // 128/18

__device__ inline unsigned short f2bf(float f) {
    unsigned u = __builtin_bit_cast(unsigned, f);
    unsigned r = (u + 0x7FFFu + ((u >> 16) & 1u)) >> 16;
    return (unsigned short)r;
}

// ---------------------------------------------------------------------------
// init: pf SoA prescaled (y,x,f0,f1,f2); sm0 = softmax(unary) in fp32 [N][36]
// and bf16-transposed smbT [48][N] with rows l*8+6 = 1.0, l*8+7 = 0.
// Also zeroes out[6] (d_out is poisoned before every call).
// ---------------------------------------------------------------------------
__global__ __launch_bounds__(256) void k_init(const float* __restrict__ unary,
                                              const float* __restrict__ feat,
                                              float* __restrict__ sm,
                                              unsigned short* __restrict__ smbT,
                                              float* __restrict__ pf,
                                              float* __restrict__ out) {
    int i = blockIdx.x * 256 + threadIdx.x;
    if (blockIdx.x == 0 && threadIdx.x < NC) out[threadIdx.x] = 0.f;
    if (i >= NPIX) return;
    int y = i / WW, x = i - y * WW;
    pf[0 * NPIX + i] = kSA * (float)y;
    pf[1 * NPIX + i] = kSA * (float)x;
    pf[2 * NPIX + i] = kSB * feat[i * 3 + 0];
    pf[3 * NPIX + i] = kSB * feat[i * 3 + 1];
    pf[4 * NPIX + i] = kSB * feat[i * 3 + 2];
    float v[NC], mx = -1e30f;
#pragma unroll
    for (int c = 0; c < NC; c++) { v[c] = unary[i * NC + c]; mx = fmaxf(mx, v[c]); }
    float sum = 0.f;
#pragma unroll
    for (int c = 0; c < NC; c++) { v[c] = __expf(v[c] - mx); sum += v[c]; }
    float inv = 1.f / sum;
#pragma unroll
    for (int l = 0; l < NC; l++) {
#pragma unroll
        for (int c = 0; c < NC; c++) {
            float s = v[c] * inv;
            sm[(size_t)i * CC + l * NC + c] = s;
            smbT[(size_t)(l * 8 + c) * NPIX + i] = f2bf(s);
        }
        smbT[(size_t)(l * 8 + 6) * NPIX + i] = 0x3F80;  // ones -> normalizer
        smbT[(size_t)(l * 8 + 7) * NPIX + i] = 0;
    }
}

// ---------------------------------------------------------------------------
// N^2 MFMA pass, both kernels, 2 i-tiles per wave (best measured config).
// Block: 4 waves; wave owns i-tiles [it0, it0+16). Grid = IBLK x JS = 1000.
// A layout: row = lane&15, k = 8*(lane>>4)+e ; B: col = lane&15, same k;
// D: col = lane&15, row = 4*(lane>>4)+reg   (verified rounds 4-6)
// Output: ONE packed array: dword = (bf16(spat)<<16) | bf16(bil)
// ---------------------------------------------------------------------------
__global__ __launch_bounds__(256) void k_bil(const unsigned short* __restrict__ smbT,
                                             const float* __restrict__ pf,
                                             unsigned* __restrict__ part) {
    int tid = threadIdx.x, bid = blockIdx.x;
    int s = bid / IBLK, ib = bid - s * IBLK;
    int j00 = s * SLICE;
    int wv = tid >> 6, lane = tid & 63, r = lane & 15, gq = lane >> 4;
    int it0 = (ib * 4 + wv) * 32;
    int iA = it0 + r, iB = iA + 16;

    const float* py = pf;
    const float* px = pf + NPIX;
    const float* p0 = pf + 2 * NPIX;
    const float* p1 = pf + 3 * NPIX;
    const float* p2 = pf + 4 * NPIX;

    float yA = py[iA], xA = px[iA], fA0 = p0[iA], fA1 = p1[iA], fA2 = p2[iA];
    float yB = py[iB], xB = px[iB], fB0 = p0[iB], fB1 = p1[iB], fB2 = p2[iB];
    const f32x2 rs2 = {kRS, kRS};

    f32x4 abA[3], asA[3], abB[3], asB[3];
#pragma unroll
    for (int t = 0; t < 3; t++) {
        abA[t] = (f32x4){0.f, 0.f, 0.f, 0.f};
        asA[t] = (f32x4){0.f, 0.f, 0.f, 0.f};
        abB[t] = (f32x4){0.f, 0.f, 0.f, 0.f};
        asB[t] = (f32x4){0.f, 0.f, 0.f, 0.f};
    }

    for (int jt = 0; jt < JTILES; jt++) {
        int jb = j00 + jt * 32 + 8 * gq;   // this lane's k-base (8-aligned)
        f32x4 yj0 = *(const f32x4*)(py + jb), yj1 = *(const f32x4*)(py + jb + 4);
        f32x4 xj0 = *(const f32x4*)(px + jb), xj1 = *(const f32x4*)(px + jb + 4);
        f32x4 c00 = *(const f32x4*)(p0 + jb), c01 = *(const f32x4*)(p0 + jb + 4);
        f32x4 c10 = *(const f32x4*)(p1 + jb), c11 = *(const f32x4*)(p1 + jb + 4);
        f32x4 c20 = *(const f32x4*)(p2 + jb), c21 = *(const f32x4*)(p2 + jb + 4);
        bfrag Bf[3];
#pragma unroll
        for (int t = 0; t < 3; t++)
            Bf[t] = *(const bfrag*)(smbT + (size_t)(16 * t + r) * NPIX + jb);

        union { unsigned u[4]; bfrag v; } Ab, As, Bb, Bs;
#pragma unroll
        for (int p = 0; p < 4; p++) {
            f32x4 ysrc = (p < 2) ? yj0 : yj1;
            f32x4 xsrc = (p < 2) ? xj0 : xj1;
            f32x4 s0 = (p < 2) ? c00 : c01;
            f32x4 s1 = (p < 2) ? c10 : c11;
            f32x4 s2 = (p < 2) ? c20 : c21;
            int e = (p & 1) * 2;
            f32x2 yj = {ysrc[e], ysrc[e + 1]};
            f32x2 xj = {xsrc[e], xsrc[e + 1]};
            f32x2 u0 = {s0[e], s0[e + 1]};
            f32x2 u1 = {s1[e], s1[e + 1]};
            f32x2 u2 = {s2[e], s2[e + 1]};

            // i-tile A
            f32x2 dy = (f32x2){yA, yA} - yj;
            f32x2 dx = (f32x2){xA, xA} - xj;
            f32x2 sp = dy * dy; sp = dx * dx + sp;
            f32x2 d0 = (f32x2){fA0, fA0} - u0;
            f32x2 d1 = (f32x2){fA1, fA1} - u1;
            f32x2 d2 = (f32x2){fA2, fA2} - u2;
            f32x2 a = d0 * d0 + sp; a = d1 * d1 + a; a = d2 * d2 + a;
            f32x2 aspt = rs2 * sp;
            float wb0 = __builtin_amdgcn_exp2f(-a[0]);
            float wb1 = __builtin_amdgcn_exp2f(-a[1]);
            float ws0 = __builtin_amdgcn_exp2f(-aspt[0]);
            float ws1 = __builtin_amdgcn_exp2f(-aspt[1]);
            asm("v_cvt_pk_bf16_f32 %0, %1, %2" : "=v"(Ab.u[p]) : "v"(wb0), "v"(wb1));
            asm("v_cvt_pk_bf16_f32 %0, %1, %2" : "=v"(As.u[p]) : "v"(ws0), "v"(ws1));

            // i-tile B
            dy = (f32x2){yB, yB} - yj;
            dx = (f32x2){xB, xB} - xj;
            sp = dy * dy; sp = dx * dx + sp;
            d0 = (f32x2){fB0, fB0} - u0;
            d1 = (f32x2){fB1, fB1} - u1;
            d2 = (f32x2){fB2, fB2} - u2;
            a = d0 * d0 + sp; a = d1 * d1 + a; a = d2 * d2 + a;
            aspt = rs2 * sp;
            wb0 = __builtin_amdgcn_exp2f(-a[0]);
            wb1 = __builtin_amdgcn_exp2f(-a[1]);
            ws0 = __builtin_amdgcn_exp2f(-aspt[0]);
            ws1 = __builtin_amdgcn_exp2f(-aspt[1]);
            asm("v_cvt_pk_bf16_f32 %0, %1, %2" : "=v"(Bb.u[p]) : "v"(wb0), "v"(wb1));
            asm("v_cvt_pk_bf16_f32 %0, %1, %2" : "=v"(Bs.u[p]) : "v"(ws0), "v"(ws1));
        }
#pragma unroll
        for (int t = 0; t < 3; t++) {
            abA[t] = __builtin_amdgcn_mfma_f32_16x16x32_bf16(Ab.v, Bf[t], abA[t], 0, 0, 0);
            asA[t] = __builtin_amdgcn_mfma_f32_16x16x32_bf16(As.v, Bf[t], asA[t], 0, 0, 0);
            abB[t] = __builtin_amdgcn_mfma_f32_16x16x32_bf16(Bb.v, Bf[t], abB[t], 0, 0, 0);
            asB[t] = __builtin_amdgcn_mfma_f32_16x16x32_bf16(Bs.v, Bf[t], asB[t], 0, 0, 0);
        }
    }
#pragma unroll
    for (int t = 0; t < 3; t++)
#pragma unroll
        for (int d = 0; d < 4; d++) {
            int irow = it0 + 4 * gq + d;
            unsigned pkA, pkB;
            asm("v_cvt_pk_bf16_f32 %0, %1, %2" : "=v"(pkA) : "v"(abA[t][d]), "v"(asA[t][d]));
            asm("v_cvt_pk_bf16_f32 %0, %1, %2" : "=v"(pkB) : "v"(abB[t][d]), "v"(asB[t][d]));
            part[((size_t)s * NPIX + irow) * CCP + 16 * t + r] = pkA;
            part[((size_t)s * NPIX + irow + 16) * CCP + 16 * t + r] = pkB;
        }
}

// ---------------------------------------------------------------------------
// update: reduce packed parts (bil = lo bf16, spat = hi bf16; norm = ch l*8+6),
// message, pairwise, q, softmax. LAST: ELBO partial sums into out[6].
// Grid is exactly 150*256 == NPIX*NC (no early returns; safe __syncthreads).
// ---------------------------------------------------------------------------
template <bool LAST>
__global__ __launch_bounds__(256) void k_update(const unsigned* __restrict__ part,
                                                const float* __restrict__ unary,
                                                const float* __restrict__ SW,
                                                const float* __restrict__ BW,
                                                const float* __restrict__ CM,
                                                const float* __restrict__ LG,
                                                float* __restrict__ sm,
                                                unsigned short* __restrict__ smbT,
                                                float* __restrict__ out) {
    __shared__ float sSW[36], sBW[36], sCM[36], sLG[36];
    __shared__ float bins[NC];
    int tid = threadIdx.x;
    if (tid < 36) { sSW[tid] = SW[tid]; sBW[tid] = BW[tid]; sCM[tid] = CM[tid]; sLG[tid] = LG[tid]; }
    if (LAST && tid < NC) bins[tid] = 0.f;
    __syncthreads();
    int t = blockIdx.x * 256 + tid;  // t = n*6 + l
    int n = t / NC, l = t - n * NC;

    float fb[NC], fs[NC], nb = 0.f, ns = 0.f;
#pragma unroll
    for (int c = 0; c < NC; c++) { fb[c] = 0.f; fs[c] = 0.f; }
    for (int s = 0; s < JS; s++) {
        const uint4* pp = (const uint4*)(part + ((size_t)s * NPIX + n) * CCP + l * 8);
        uint4 v0 = pp[0], v1 = pp[1];
        unsigned d[7] = {v0.x, v0.y, v0.z, v0.w, v1.x, v1.y, v1.z};
#pragma unroll
        for (int c = 0; c < NC; c++) {
            fb[c] += __builtin_bit_cast(float, d[c] << 16);
            fs[c] += __builtin_bit_cast(float, d[c] & 0xFFFF0000u);
        }
        nb += __builtin_bit_cast(float, d[6] << 16);
        ns += __builtin_bit_cast(float, d[6] & 0xFFFF0000u);
    }
    float invb = 1.f / nb, invs = 1.f / ns;
#pragma unroll
    for (int c = 0; c < NC; c++) { fb[c] *= invb; fs[c] *= invs; }

    float m[NC];
#pragma unroll
    for (int c = 0; c < NC; c++) {
        float a = 0.f;
#pragma unroll
        for (int cp = 0; cp < NC; cp++)
            a += sSW[c * NC + cp] * fs[cp] + sBW[c * NC + cp] * fb[cp];
        m[c] = a;
    }
    const float* up = unary + (size_t)n * NC;
    if (!LAST) {
        float qv[NC], mxq = -1e30f;
#pragma unroll
        for (int c = 0; c < NC; c++) {
            float pw = 0.f;
#pragma unroll
            for (int cp = 0; cp < NC; cp++) pw += sCM[c * NC + cp] * m[cp];
            qv[c] = up[c] + sLG[c * NC + l] - pw;
            mxq = fmaxf(mxq, qv[c]);
        }
        float e[NC], ssum = 0.f;
#pragma unroll
        for (int c = 0; c < NC; c++) { e[c] = __expf(qv[c] - mxq); ssum += e[c]; }
        float inv = 1.f / ssum;
        float* sp = sm + (size_t)n * CC + l * NC;
#pragma unroll
        for (int c = 0; c < NC; c++) {
            float sv = e[c] * inv;
            sp[c] = sv;
            smbT[(size_t)(l * 8 + c) * NPIX + n] = f2bf(sv);
        }
    } else {
        const float* sp = sm + (size_t)n * CC + l * NC;
        float v = 0.f;
#pragma unroll
        for (int c = 0; c < NC; c++) {
            float sv = sp[c];
            v += sv * (up[c] + sLG[c * NC + l] - logf(sv + 1e-10f) - m[c]);
        }
        atomicAdd(&bins[l], v);
        __syncthreads();
        if (tid < NC) atomicAdd(&out[tid], bins[tid]);
    }
}

// ---------------------------------------------------------------------------
extern "C" void kernel_launch(void* const* d_in, const int* in_sizes, int n_in,
                              void* d_out, int out_size, void* d_ws, size_t ws_size,
                              hipStream_t stream) {
    const float* unary = (const float*)d_in[0];  // [N][6]
    const float* feat  = (const float*)d_in[1];  // [N][3]
    const float* CM    = (const float*)d_in[2];  // [6][6]
    const float* LG    = (const float*)d_in[3];
    const float* SW    = (const float*)d_in[4];
    const float* BW    = (const float*)d_in[5];
    float* out = (float*)d_out;

    float* ws = (float*)d_ws;
    float* pf = ws;                                     // 5N
    float* sm = pf + (size_t)5 * NPIX;                  // 36N fp32
    unsigned short* smbT = (unsigned short*)(sm + (size_t)CC * NPIX);  // 48 x N bf16
    unsigned* part = (unsigned*)(ws + (size_t)65 * NPIX);  // JS*N*48 dwords (packed bf16 pair)

    k_init<<<25, 256, 0, stream>>>(unary, feat, sm, smbT, pf, out);

    for (int it = 0; it < NUM_ITER; it++) {
        k_bil<<<IBLK * JS, 256, 0, stream>>>(smbT, pf, part);
        if (it < NUM_ITER - 1)
            k_update<false><<<150, 256, 0, stream>>>(part, unary, SW, BW, CM, LG,
                                                     sm, smbT, out);
        else
            k_update<true><<<150, 256, 0, stream>>>(part, unary, SW, BW, CM, LG,
                                                    sm, smbT, out);
    }
}